// Round 6
// baseline (281.260 us; speedup 1.0000x reference)
//
#include <hip/hip_runtime.h>
#include <math.h>

#define LSEQ 1024
#define DM   768
#define NS   16
#define DR   48
#define BSZ  2
#define NC   64           // chunks over L
#define LC   (LSEQ/NC)    // 16

typedef __bf16 bf16x4 __attribute__((ext_vector_type(4)));
typedef __bf16 bf16x8 __attribute__((ext_vector_type(8)));
typedef float  f32x4  __attribute__((ext_vector_type(4)));

// ---------------- GEMM: f32 in/out, bf16 MFMA, reg-prefetch, split epilogue --------
__global__ __launch_bounds__(256) void gemm_bf16(const float* __restrict__ A,
                                                 const float* __restrict__ B,
                                                 float* __restrict__ C,
                                                 float* __restrict__ C1,
                                                 int split,
                                                 int K, int lda, int ldb, int ldc) {
    __shared__ __align__(16) __bf16 As[128][40];   // As[m][k], row padded to 80 B
    __shared__ __align__(16) __bf16 Bs[128][40];   // Bs[n][k] (transposed in staging)
    const int tid  = threadIdx.x;
    const int lane = tid & 63;
    const int wave = tid >> 6;
    const int wr = (wave >> 1) * 64, wc = (wave & 1) * 64;
    const int r = lane & 15, q = lane >> 4;
    const int m0 = blockIdx.y * 128, n0 = blockIdx.x * 128;

    const int arow = tid >> 3, ac4 = (tid & 7) * 4;
    const int nq = (tid & 7) + (tid >> 6) * 8;   // n-quad
    const int kg = (tid >> 3) & 7;               // k-quad

    f32x4 zero = {0.f, 0.f, 0.f, 0.f};
    f32x4 acc[4][4];
    #pragma unroll
    for (int mt = 0; mt < 4; ++mt)
        #pragma unroll
        for (int nt = 0; nt < 4; ++nt) acc[mt][nt] = zero;

    f32x4 a_pf[4], b_pf[4];
    #pragma unroll
    for (int j = 0; j < 4; ++j)
        a_pf[j] = *(const f32x4*)(A + (size_t)(m0 + arow + 32 * j) * lda + ac4);
    #pragma unroll
    for (int i = 0; i < 4; ++i)
        b_pf[i] = *(const f32x4*)(B + (size_t)(kg * 4 + i) * ldb + n0 + nq * 4);

    const int KT = K / 32;
    for (int kt = 0; kt < KT; ++kt) {
        #pragma unroll
        for (int j = 0; j < 4; ++j) {
            bf16x4 pk = {(__bf16)a_pf[j][0], (__bf16)a_pf[j][1],
                         (__bf16)a_pf[j][2], (__bf16)a_pf[j][3]};
            *(bf16x4*)&As[arow + 32 * j][ac4] = pk;
        }
        #pragma unroll
        for (int c = 0; c < 4; ++c) {
            bf16x4 pk = {(__bf16)b_pf[0][c], (__bf16)b_pf[1][c],
                         (__bf16)b_pf[2][c], (__bf16)b_pf[3][c]};
            *(bf16x4*)&Bs[nq * 4 + c][kg * 4] = pk;
        }
        __syncthreads();
        if (kt + 1 < KT) {
            int k0 = (kt + 1) * 32;
            #pragma unroll
            for (int j = 0; j < 4; ++j)
                a_pf[j] = *(const f32x4*)(A + (size_t)(m0 + arow + 32 * j) * lda + k0 + ac4);
            #pragma unroll
            for (int i = 0; i < 4; ++i)
                b_pf[i] = *(const f32x4*)(B + (size_t)(k0 + kg * 4 + i) * ldb + n0 + nq * 4);
        }
        bf16x8 af[4], bf[4];
        #pragma unroll
        for (int t = 0; t < 4; ++t) {
            af[t] = *(const bf16x8*)&As[wr + t * 16 + r][q * 8];
            bf[t] = *(const bf16x8*)&Bs[wc + t * 16 + r][q * 8];
        }
        #pragma unroll
        for (int mt = 0; mt < 4; ++mt)
            #pragma unroll
            for (int nt = 0; nt < 4; ++nt)
                acc[mt][nt] = __builtin_amdgcn_mfma_f32_16x16x32_bf16(
                    af[mt], bf[nt], acc[mt][nt], 0, 0, 0);
        __syncthreads();
    }
    float* Cd = C;
    int nbase = n0;
    if (n0 >= split) { Cd = C1; nbase = n0 - split; }
    #pragma unroll
    for (int mt = 0; mt < 4; ++mt) {
        #pragma unroll
        for (int nt = 0; nt < 4; ++nt) {
            int col  = nbase + wc + nt * 16 + r;
            int rowb = m0 + wr + mt * 16 + q * 4;
            #pragma unroll
            for (int rr = 0; rr < 4; ++rr)
                Cd[(size_t)(rowb + rr) * ldc + col] = acc[mt][nt][rr];
        }
    }
}

// ------- fused: u = silu(depthwise conv(xs)+cb);  xp = u @ W_x  (bf16 MFMA) -------
// M-tile 64 rows (4 waves x 16), N=80 (5 col-tiles/wave), grid = R/64 = 32.
// Per K-slice of 32 channels: stage xs rows [m0-3, m0+64) x 32 cols, compute conv+silu
// in-kernel, feed As2 directly, and write u (f32) once for the scan.
__global__ __launch_bounds__(256) void convwx(const float* __restrict__ xs,
                                              const float* __restrict__ cw,
                                              const float* __restrict__ cb,
                                              const float* __restrict__ Wx,
                                              float* __restrict__ u,
                                              float* __restrict__ xp) {
    __shared__ __align__(16) float sXs[67][36];    // halo rows; stride 36 keeps 16B align
    __shared__ __align__(16) __bf16 As2[64][40];
    __shared__ __align__(16) __bf16 Ws[80][40];
    const int tid  = threadIdx.x;
    const int lane = tid & 63;
    const int wave = tid >> 6;
    const int r = lane & 15, q = lane >> 4;
    const int m0 = blockIdx.x * 64;
    const int nq = tid % 20, kq = tid / 20;      // W transpose task (tid<160)
    const int cc = tid & 31, ib = tid >> 5;      // conv task: col cc, rows ib+8p

    f32x4 zero = {0.f, 0.f, 0.f, 0.f};
    f32x4 acc[5];
    #pragma unroll
    for (int nt = 0; nt < 5; ++nt) acc[nt] = zero;

    for (int kt = 0; kt < 24; ++kt) {
        const int k0 = kt * 32;
        // stage xs tile (67 rows x 32 cols)
        for (int i = tid; i < 67 * 8; i += 256) {
            int row = i >> 3, c4 = (i & 7) * 4;
            int grow = m0 - 3 + row;
            f32x4 v = (grow >= 0) ? *(const f32x4*)(xs + (size_t)grow * DM + k0 + c4) : zero;
            *(f32x4*)&sXs[row][c4] = v;
        }
        // stage W (transposed to Ws[n][k])
        if (tid < 160) {
            f32x4 w_pf[4];
            #pragma unroll
            for (int i = 0; i < 4; ++i)
                w_pf[i] = *(const f32x4*)(Wx + (size_t)(k0 + kq * 4 + i) * 80 + nq * 4);
            #pragma unroll
            for (int c = 0; c < 4; ++c) {
                bf16x4 pk = {(__bf16)w_pf[0][c], (__bf16)w_pf[1][c],
                             (__bf16)w_pf[2][c], (__bf16)w_pf[3][c]};
                *(bf16x4*)&Ws[nq * 4 + c][kq * 4] = pk;
            }
        }
        __syncthreads();
        // conv + silu -> u global + As2 (bf16)
        {
            f32x4 cwv = *(const f32x4*)(cw + (size_t)(k0 + cc) * 4);
            float cbv = cb[k0 + cc];
            #pragma unroll
            for (int p = 0; p < 8; ++p) {
                int i = ib + p * 8;                    // output row 0..63
                int l = (m0 + i) & (LSEQ - 1);
                float a = cbv;
                #pragma unroll
                for (int k = 0; k < 4; ++k)
                    if (l - 3 + k >= 0) a += sXs[i + k][cc] * cwv[k];
                float uu = a / (1.f + expf(-a));
                u[(size_t)(m0 + i) * DM + k0 + cc] = uu;
                As2[i][cc] = (__bf16)uu;
            }
        }
        __syncthreads();
        // MFMA
        bf16x8 af = *(const bf16x8*)&As2[wave * 16 + r][q * 8];
        #pragma unroll
        for (int nt = 0; nt < 5; ++nt) {
            bf16x8 bfr = *(const bf16x8*)&Ws[nt * 16 + r][q * 8];
            acc[nt] = __builtin_amdgcn_mfma_f32_16x16x32_bf16(af, bfr, acc[nt], 0, 0, 0);
        }
        __syncthreads();
    }
    #pragma unroll
    for (int nt = 0; nt < 5; ++nt) {
        int col  = nt * 16 + r;
        int rowb = m0 + wave * 16 + q * 4;
        #pragma unroll
        for (int rr = 0; rr < 4; ++rr)
            xp[(size_t)(rowb + rr) * 80 + col] = acc[nt][rr];
    }
}

// ---------------- delta = clip(softplus(xp[:,:48] @ W_delta + b_delta)) ------------
__global__ __launch_bounds__(256) void gemm_delta(const float* __restrict__ xp,
                                                  const float* __restrict__ Wd,
                                                  const float* __restrict__ bd,
                                                  float* __restrict__ delta) {
    __shared__ __align__(16) __bf16 As[128][40];
    __shared__ __align__(16) __bf16 Bs[128][40];
    const int tid  = threadIdx.x;
    const int lane = tid & 63;
    const int wave = tid >> 6;
    const int wr = (wave >> 1) * 64, wc = (wave & 1) * 64;
    const int r = lane & 15, q = lane >> 4;
    const int m0 = blockIdx.y * 128, n0 = blockIdx.x * 128;
    const int arow = tid >> 1, ak16 = (tid & 1) * 16;
    const int nq = tid & 31, kq = tid >> 5;

    f32x4 zero = {0.f, 0.f, 0.f, 0.f};
    f32x4 acc[4][4];
    #pragma unroll
    for (int mt = 0; mt < 4; ++mt)
        #pragma unroll
        for (int nt = 0; nt < 4; ++nt) acc[mt][nt] = zero;

    for (int k0 = 0; k0 < 64; k0 += 32) {
        #pragma unroll
        for (int j = 0; j < 4; ++j) {
            int k = k0 + ak16 + j * 4;
            f32x4 v = (k < DR) ? *(const f32x4*)(xp + (size_t)(m0 + arow) * 80 + k) : zero;
            bf16x4 pk = {(__bf16)v[0], (__bf16)v[1], (__bf16)v[2], (__bf16)v[3]};
            *(bf16x4*)&As[arow][ak16 + j * 4] = pk;
        }
        {
            f32x4 bv[4];
            #pragma unroll
            for (int i = 0; i < 4; ++i) {
                int k = k0 + kq * 4 + i;
                bv[i] = (k < DR) ? *(const f32x4*)(Wd + (size_t)k * DM + n0 + nq * 4) : zero;
            }
            #pragma unroll
            for (int c = 0; c < 4; ++c) {
                bf16x4 pk = {(__bf16)bv[0][c], (__bf16)bv[1][c],
                             (__bf16)bv[2][c], (__bf16)bv[3][c]};
                *(bf16x4*)&Bs[nq * 4 + c][kq * 4] = pk;
            }
        }
        __syncthreads();
        bf16x8 af[4], bf[4];
        #pragma unroll
        for (int t = 0; t < 4; ++t) {
            af[t] = *(const bf16x8*)&As[wr + t * 16 + r][q * 8];
            bf[t] = *(const bf16x8*)&Bs[wc + t * 16 + r][q * 8];
        }
        #pragma unroll
        for (int mt = 0; mt < 4; ++mt)
            #pragma unroll
            for (int nt = 0; nt < 4; ++nt)
                acc[mt][nt] = __builtin_amdgcn_mfma_f32_16x16x32_bf16(
                    af[mt], bf[nt], acc[mt][nt], 0, 0, 0);
        __syncthreads();
    }
    #pragma unroll
    for (int mt = 0; mt < 4; ++mt) {
        #pragma unroll
        for (int nt = 0; nt < 4; ++nt) {
            int col  = n0 + wc + nt * 16 + r;
            int rowb = m0 + wr + mt * 16 + q * 4;
            float bcol = bd[col];
            #pragma unroll
            for (int rr = 0; rr < 4; ++rr) {
                float z = acc[mt][nt][rr] + bcol;
                float sp = (z > 20.f) ? z : log1pf(expf(z));
                sp = fminf(fmaxf(sp, 1e-4f), 0.1f);
                delta[(size_t)(rowb + rr) * DM + col] = sp;
            }
        }
    }
}

// ---------------- fully-fused chunked selective scan ----------------
// Block = 256 threads = 64 chunks x 4 d; grid = BSZ*(DM/4) = 384.
// Phase1: per-chunk local scan (h_in=0) -> E, h_end, pd into LDS.
// Combine: wave0 chains H over chunks (batched-8 LDS); wave1 prefixes pd.
// Phase3: replay seeded with H_in; corr, C-contraction, D-skip, silu gate.
// Numerically identical to the previous 3-kernel pipeline (same orders).
// g aliases u: per-thread read-before-write; phase1 u-reads are barrier-ordered
// before phase3 writes; blocks own disjoint (b,d) ranges.
__global__ __launch_bounds__(256) void scan_fused(const float* __restrict__ delta,
                                                  const float* __restrict__ u,
                                                  const float* __restrict__ xp,
                                                  const float* __restrict__ res,
                                                  const float* __restrict__ A_log,
                                                  const float* __restrict__ Dp,
                                                  float* __restrict__ g) {
    __shared__ float sE[NS][NC + 1][4];   // [n][ch][dsub], ch padded to 65
    __shared__ float sH[NS][NC + 1][4];
    __shared__ float sPD[NC][5];
    __shared__ float sTD[4];
    const int tid  = threadIdx.x;
    const int ch   = tid >> 2;
    const int dsub = tid & 3;
    const int blk  = blockIdx.x;
    const int b    = blk / (DM / 4);
    const int d    = (blk % (DM / 4)) * 4 + dsub;
    const int l0   = ch * LC;

    float c[NS];
    #pragma unroll
    for (int n = 0; n < NS; ++n) c[n] = -__expf(A_log[d * NS + n]);

    // ---- phase 1: local scan ----
    float h[NS], ep[NS];
    #pragma unroll
    for (int n = 0; n < NS; ++n) { h[n] = 0.f; ep[n] = 1.f; }
    float pd = 0.f;
    for (int l = 0; l < LC; ++l) {
        size_t rr = (size_t)(b * LSEQ + l0 + l);
        float dlt = delta[rr * DM + d];
        float uu  = u[rr * DM + d];
        pd += dlt;
        float du = dlt * uu;
        f32x4 Bv[4];
        #pragma unroll
        for (int i = 0; i < 4; ++i)
            Bv[i] = *(const f32x4*)(xp + rr * 80 + DR + i * 4);
        #pragma unroll
        for (int n = 0; n < NS; ++n) {
            float e = __expf(c[n] * dlt);
            h[n]  = e * h[n] + du * Bv[n >> 2][n & 3];
            ep[n] *= e;
        }
    }
    #pragma unroll
    for (int n = 0; n < NS; ++n) {
        sE[n][ch][dsub] = ep[n];
        sH[n][ch][dsub] = h[n];
    }
    sPD[ch][dsub] = pd;
    __syncthreads();

    // ---- combine (wave0: H chains; wave1 lanes 0-3: pd prefix) ----
    if (tid < 64) {
        const int ds2 = tid & 3, n2 = tid >> 2;
        float H = 0.f;
        for (int cg = 0; cg < NC; cg += 8) {
            float ee[8], hh[8];
            #pragma unroll
            for (int j = 0; j < 8; ++j) {
                ee[j] = sE[n2][cg + j][ds2];
                hh[j] = sH[n2][cg + j][ds2];
            }
            #pragma unroll
            for (int j = 0; j < 8; ++j) {
                sH[n2][cg + j][ds2] = H;      // H_in for chunk cg+j
                H = ee[j] * H + hh[j];
            }
        }
    } else if (tid < 68) {
        const int ds2 = tid - 64;
        float p = 0.f;
        for (int cg = 0; cg < NC; cg += 8) {
            float ss[8];
            #pragma unroll
            for (int j = 0; j < 8; ++j) ss[j] = sPD[cg + j][ds2];
            #pragma unroll
            for (int j = 0; j < 8; ++j) { sPD[cg + j][ds2] = p; p += ss[j]; }
        }
        sTD[ds2] = p;
    }
    __syncthreads();

    // ---- phase 3: replay + output ----
    #pragma unroll
    for (int n = 0; n < NS; ++n) h[n] = sH[n][ch][dsub];
    pd = sPD[ch][dsub];
    const float td = sTD[dsub];
    const float dp = Dp[d];

    for (int l = 0; l < LC; ++l) {
        size_t rr = (size_t)(b * LSEQ + l0 + l);
        float dlt = delta[rr * DM + d];
        float uu  = u[rr * DM + d];
        float rv  = res[rr * DM + d];
        pd += dlt;
        float du = dlt * uu;
        float x = td - pd;                        // >= 0; exactly 0 at l = L-1
        f32x4 Bv[4], Cv[4];
        #pragma unroll
        for (int i = 0; i < 4; ++i) {
            Bv[i] = *(const f32x4*)(xp + rr * 80 + DR + i * 4);
            Cv[i] = *(const f32x4*)(xp + rr * 80 + DR + NS + i * 4);
        }
        float y = 0.f;
        #pragma unroll
        for (int n = 0; n < NS; ++n) {
            float e = __expf(c[n] * dlt);
            h[n] = e * h[n] + du * Bv[n >> 2][n & 3];
            float P = __expf(-c[n] * x);          // exp(-S); overflow->inf
            float den = 1.0f + 1e-12f * P;        // inf -> corr 0, matches ref
            y += h[n] * Cv[n >> 2][n & 3] * __builtin_amdgcn_rcpf(den);
        }
        y += uu * dp;
        float sig = __builtin_amdgcn_rcpf(1.f + __expf(-rv));
        g[rr * DM + d] = y * rv * sig;
    }
}

extern "C" void kernel_launch(void* const* d_in, const int* in_sizes, int n_in,
                              void* d_out, int out_size, void* d_ws, size_t ws_size,
                              hipStream_t stream) {
    const float* x       = (const float*)d_in[0];
    const float* W_in    = (const float*)d_in[1];
    const float* conv_w  = (const float*)d_in[2];
    const float* conv_b  = (const float*)d_in[3];
    const float* W_x     = (const float*)d_in[4];
    const float* W_delta = (const float*)d_in[5];
    const float* b_delta = (const float*)d_in[6];
    const float* A_log   = (const float*)d_in[7];
    const float* D_param = (const float*)d_in[8];
    const float* W_out   = (const float*)d_in[9];
    float* out = (float*)d_out;
    float* ws  = (float*)d_ws;

    const int R = BSZ * LSEQ;  // 2048

    // Workspace: 25.8 MiB. g aliases u (scan_fused read-before-write).
    float* xs    = ws;                           // R*768
    float* res   = xs    + (size_t)R * DM;       // R*768
    float* u     = res   + (size_t)R * DM;       // R*768
    float* xp    = u     + (size_t)R * DM;       // R*80
    float* delta = xp    + (size_t)R * 80;       // R*768
    float* g     = u;                            // ALIAS

    // 1) xr = x @ W_in, split epilogue -> xs (cols 0..767), res (cols 768..1535)
    gemm_bf16<<<dim3(1536 / 128, R / 128), 256, 0, stream>>>(
        x, W_in, xs, res, 768, 768, 768, 1536, 768);
    // 2+3) fused: u = silu(conv(xs)+cb); xp = u @ W_x
    convwx<<<R / 64, 256, 0, stream>>>(xs, conv_w, conv_b, W_x, u, xp);
    // 4) delta (bf16 MFMA, K=48 padded, fused softplus epilogue)
    gemm_delta<<<dim3(DM / 128, R / 128), 256, 0, stream>>>(xp, W_delta, b_delta, delta);
    // 5) fully-fused chunked scan + D skip + gate
    scan_fused<<<BSZ * (DM / 4), 256, 0, stream>>>(delta, u, xp, res, A_log, D_param, g);
    // 6) out = g @ W_out
    gemm_bf16<<<dim3(768 / 128, R / 128), 256, 0, stream>>>(
        g, W_out, out, out, 1 << 30, 768, 768, 768, 768);
}

// Round 7
// 213.055 us; speedup vs baseline: 1.3201x; 1.3201x over previous
//
#include <hip/hip_runtime.h>
#include <math.h>

#define LSEQ 1024
#define DM   768
#define NS   16
#define DR   48
#define BSZ  2
#define NC   64           // chunks over L
#define LC   (LSEQ/NC)    // 16
#define KSP  6            // K-splits for the wx GEMM (768/6 = 128)

typedef __bf16 bf16x4 __attribute__((ext_vector_type(4)));
typedef __bf16 bf16x8 __attribute__((ext_vector_type(8)));
typedef float  f32x4  __attribute__((ext_vector_type(4)));

// ---------------- GEMM: f32 in/out, bf16 MFMA, reg-prefetch, split epilogue --------
__global__ __launch_bounds__(256) void gemm_bf16(const float* __restrict__ A,
                                                 const float* __restrict__ B,
                                                 float* __restrict__ C,
                                                 float* __restrict__ C1,
                                                 int split,
                                                 int K, int lda, int ldb, int ldc) {
    __shared__ __align__(16) __bf16 As[128][40];   // As[m][k], row padded to 80 B
    __shared__ __align__(16) __bf16 Bs[128][40];   // Bs[n][k] (transposed in staging)
    const int tid  = threadIdx.x;
    const int lane = tid & 63;
    const int wave = tid >> 6;
    const int wr = (wave >> 1) * 64, wc = (wave & 1) * 64;
    const int r = lane & 15, q = lane >> 4;
    const int m0 = blockIdx.y * 128, n0 = blockIdx.x * 128;

    const int arow = tid >> 3, ac4 = (tid & 7) * 4;
    const int nq = (tid & 7) + (tid >> 6) * 8;   // n-quad
    const int kg = (tid >> 3) & 7;               // k-quad

    f32x4 zero = {0.f, 0.f, 0.f, 0.f};
    f32x4 acc[4][4];
    #pragma unroll
    for (int mt = 0; mt < 4; ++mt)
        #pragma unroll
        for (int nt = 0; nt < 4; ++nt) acc[mt][nt] = zero;

    f32x4 a_pf[4], b_pf[4];
    #pragma unroll
    for (int j = 0; j < 4; ++j)
        a_pf[j] = *(const f32x4*)(A + (size_t)(m0 + arow + 32 * j) * lda + ac4);
    #pragma unroll
    for (int i = 0; i < 4; ++i)
        b_pf[i] = *(const f32x4*)(B + (size_t)(kg * 4 + i) * ldb + n0 + nq * 4);

    const int KT = K / 32;
    for (int kt = 0; kt < KT; ++kt) {
        #pragma unroll
        for (int j = 0; j < 4; ++j) {
            bf16x4 pk = {(__bf16)a_pf[j][0], (__bf16)a_pf[j][1],
                         (__bf16)a_pf[j][2], (__bf16)a_pf[j][3]};
            *(bf16x4*)&As[arow + 32 * j][ac4] = pk;
        }
        #pragma unroll
        for (int c = 0; c < 4; ++c) {
            bf16x4 pk = {(__bf16)b_pf[0][c], (__bf16)b_pf[1][c],
                         (__bf16)b_pf[2][c], (__bf16)b_pf[3][c]};
            *(bf16x4*)&Bs[nq * 4 + c][kg * 4] = pk;
        }
        __syncthreads();
        if (kt + 1 < KT) {
            int k0 = (kt + 1) * 32;
            #pragma unroll
            for (int j = 0; j < 4; ++j)
                a_pf[j] = *(const f32x4*)(A + (size_t)(m0 + arow + 32 * j) * lda + k0 + ac4);
            #pragma unroll
            for (int i = 0; i < 4; ++i)
                b_pf[i] = *(const f32x4*)(B + (size_t)(k0 + kg * 4 + i) * ldb + n0 + nq * 4);
        }
        bf16x8 af[4], bf[4];
        #pragma unroll
        for (int t = 0; t < 4; ++t) {
            af[t] = *(const bf16x8*)&As[wr + t * 16 + r][q * 8];
            bf[t] = *(const bf16x8*)&Bs[wc + t * 16 + r][q * 8];
        }
        #pragma unroll
        for (int mt = 0; mt < 4; ++mt)
            #pragma unroll
            for (int nt = 0; nt < 4; ++nt)
                acc[mt][nt] = __builtin_amdgcn_mfma_f32_16x16x32_bf16(
                    af[mt], bf[nt], acc[mt][nt], 0, 0, 0);
        __syncthreads();
    }
    float* Cd = C;
    int nbase = n0;
    if (n0 >= split) { Cd = C1; nbase = n0 - split; }
    #pragma unroll
    for (int mt = 0; mt < 4; ++mt) {
        #pragma unroll
        for (int nt = 0; nt < 4; ++nt) {
            int col  = nbase + wc + nt * 16 + r;
            int rowb = m0 + wr + mt * 16 + q * 4;
            #pragma unroll
            for (int rr = 0; rr < 4; ++rr)
                Cd[(size_t)(rowb + rr) * ldc + col] = acc[mt][nt][rr];
        }
    }
}

// ---------------- depthwise causal conv (K=4) + SiLU ----------------
__global__ __launch_bounds__(256) void conv_silu(const float* __restrict__ xs,
                                                 const float* __restrict__ cw,
                                                 const float* __restrict__ cb,
                                                 float* __restrict__ u) {
    const int idx = blockIdx.x * 256 + threadIdx.x;  // r*DM + d
    const int r = idx / DM;
    const int d = idx - r * DM;
    const int l = r & (LSEQ - 1);
    float acc = cb[d];
    #pragma unroll
    for (int k = 0; k < 4; ++k) {
        int ll = l - 3 + k;
        if (ll >= 0)
            acc += xs[(size_t)(r - 3 + k) * DM + d] * cw[d * 4 + k];
    }
    float sig = 1.f / (1.f + expf(-acc));
    u[idx] = acc * sig;
}

// ---------------- xp partials: split-K bf16 MFMA (2048 x 80, K=768/KSP) ------------
// grid = (R/64, KSP) = (32, 6) = 192 blocks; each block does 4 K-steps of 32.
__global__ __launch_bounds__(256) void gemm_wx_sk(const float* __restrict__ U,
                                                  const float* __restrict__ Wx,
                                                  float* __restrict__ xpp) {
    __shared__ __align__(16) __bf16 As2[64][40];
    __shared__ __align__(16) __bf16 Ws[80][40];
    const int tid  = threadIdx.x;
    const int lane = tid & 63;
    const int wave = tid >> 6;
    const int r = lane & 15, q = lane >> 4;
    const int m0 = blockIdx.x * 64;
    const int ks = blockIdx.y;
    const int kbase = ks * (768 / KSP);          // 128
    const int arow = tid >> 2, ak8 = (tid & 3) * 8;
    const int nq = tid % 20, kq = tid / 20;      // W transpose task (tid<160)

    f32x4 acc[5];
    #pragma unroll
    for (int nt = 0; nt < 5; ++nt) acc[nt] = {0.f, 0.f, 0.f, 0.f};

    f32x4 a_pf0, a_pf1, w_pf[4];
    a_pf0 = *(const f32x4*)(U + (size_t)(m0 + arow) * DM + kbase + ak8);
    a_pf1 = *(const f32x4*)(U + (size_t)(m0 + arow) * DM + kbase + ak8 + 4);
    if (tid < 160) {
        #pragma unroll
        for (int i = 0; i < 4; ++i)
            w_pf[i] = *(const f32x4*)(Wx + (size_t)(kbase + kq * 4 + i) * 80 + nq * 4);
    }

    const int KT = (768 / KSP) / 32;             // 4
    for (int kt = 0; kt < KT; ++kt) {
        bf16x4 p0 = {(__bf16)a_pf0[0], (__bf16)a_pf0[1], (__bf16)a_pf0[2], (__bf16)a_pf0[3]};
        bf16x4 p1 = {(__bf16)a_pf1[0], (__bf16)a_pf1[1], (__bf16)a_pf1[2], (__bf16)a_pf1[3]};
        *(bf16x4*)&As2[arow][ak8]     = p0;
        *(bf16x4*)&As2[arow][ak8 + 4] = p1;
        if (tid < 160) {
            #pragma unroll
            for (int c = 0; c < 4; ++c) {
                bf16x4 pk = {(__bf16)w_pf[0][c], (__bf16)w_pf[1][c],
                             (__bf16)w_pf[2][c], (__bf16)w_pf[3][c]};
                *(bf16x4*)&Ws[nq * 4 + c][kq * 4] = pk;
            }
        }
        __syncthreads();
        if (kt + 1 < KT) {
            int k0 = kbase + (kt + 1) * 32;
            a_pf0 = *(const f32x4*)(U + (size_t)(m0 + arow) * DM + k0 + ak8);
            a_pf1 = *(const f32x4*)(U + (size_t)(m0 + arow) * DM + k0 + ak8 + 4);
            if (tid < 160) {
                #pragma unroll
                for (int i = 0; i < 4; ++i)
                    w_pf[i] = *(const f32x4*)(Wx + (size_t)(k0 + kq * 4 + i) * 80 + nq * 4);
            }
        }
        bf16x8 af = *(const bf16x8*)&As2[wave * 16 + r][q * 8];
        #pragma unroll
        for (int nt = 0; nt < 5; ++nt) {
            bf16x8 bfr = *(const bf16x8*)&Ws[nt * 16 + r][q * 8];
            acc[nt] = __builtin_amdgcn_mfma_f32_16x16x32_bf16(af, bfr, acc[nt], 0, 0, 0);
        }
        __syncthreads();
    }
    #pragma unroll
    for (int nt = 0; nt < 5; ++nt) {
        int col  = nt * 16 + r;
        int rowb = m0 + wave * 16 + q * 4;
        #pragma unroll
        for (int rr = 0; rr < 4; ++rr)
            xpp[((size_t)ks * (BSZ * LSEQ) + rowb + rr) * 80 + col] = acc[nt][rr];
    }
}

// ---------------- xp = sum over KSP partials (deterministic s-order) ----------------
// grid = R*80/4/256 = 160 blocks; f32x4 lanes.
__global__ __launch_bounds__(256) void reduce_xp(const float* __restrict__ xpp,
                                                 float* __restrict__ xp) {
    const size_t i = ((size_t)blockIdx.x * 256 + threadIdx.x) * 4;
    f32x4 s = *(const f32x4*)(xpp + i);
    #pragma unroll
    for (int k = 1; k < KSP; ++k) {
        f32x4 v = *(const f32x4*)(xpp + (size_t)k * (BSZ * LSEQ) * 80 + i);
        s[0] += v[0]; s[1] += v[1]; s[2] += v[2]; s[3] += v[3];
    }
    *(f32x4*)(xp + i) = s;
}

// ---------------- delta = clip(softplus(xp[:,:48] @ W_delta + b_delta)) ------------
__global__ __launch_bounds__(256) void gemm_delta(const float* __restrict__ xp,
                                                  const float* __restrict__ Wd,
                                                  const float* __restrict__ bd,
                                                  float* __restrict__ delta) {
    __shared__ __align__(16) __bf16 As[128][40];
    __shared__ __align__(16) __bf16 Bs[128][40];
    const int tid  = threadIdx.x;
    const int lane = tid & 63;
    const int wave = tid >> 6;
    const int wr = (wave >> 1) * 64, wc = (wave & 1) * 64;
    const int r = lane & 15, q = lane >> 4;
    const int m0 = blockIdx.y * 128, n0 = blockIdx.x * 128;
    const int arow = tid >> 1, ak16 = (tid & 1) * 16;
    const int nq = tid & 31, kq = tid >> 5;

    f32x4 zero = {0.f, 0.f, 0.f, 0.f};
    f32x4 acc[4][4];
    #pragma unroll
    for (int mt = 0; mt < 4; ++mt)
        #pragma unroll
        for (int nt = 0; nt < 4; ++nt) acc[mt][nt] = zero;

    for (int k0 = 0; k0 < 64; k0 += 32) {
        #pragma unroll
        for (int j = 0; j < 4; ++j) {
            int k = k0 + ak16 + j * 4;
            f32x4 v = (k < DR) ? *(const f32x4*)(xp + (size_t)(m0 + arow) * 80 + k) : zero;
            bf16x4 pk = {(__bf16)v[0], (__bf16)v[1], (__bf16)v[2], (__bf16)v[3]};
            *(bf16x4*)&As[arow][ak16 + j * 4] = pk;
        }
        {
            f32x4 bv[4];
            #pragma unroll
            for (int i = 0; i < 4; ++i) {
                int k = k0 + kq * 4 + i;
                bv[i] = (k < DR) ? *(const f32x4*)(Wd + (size_t)k * DM + n0 + nq * 4) : zero;
            }
            #pragma unroll
            for (int c = 0; c < 4; ++c) {
                bf16x4 pk = {(__bf16)bv[0][c], (__bf16)bv[1][c],
                             (__bf16)bv[2][c], (__bf16)bv[3][c]};
                *(bf16x4*)&Bs[nq * 4 + c][kq * 4] = pk;
            }
        }
        __syncthreads();
        bf16x8 af[4], bf[4];
        #pragma unroll
        for (int t = 0; t < 4; ++t) {
            af[t] = *(const bf16x8*)&As[wr + t * 16 + r][q * 8];
            bf[t] = *(const bf16x8*)&Bs[wc + t * 16 + r][q * 8];
        }
        #pragma unroll
        for (int mt = 0; mt < 4; ++mt)
            #pragma unroll
            for (int nt = 0; nt < 4; ++nt)
                acc[mt][nt] = __builtin_amdgcn_mfma_f32_16x16x32_bf16(
                    af[mt], bf[nt], acc[mt][nt], 0, 0, 0);
        __syncthreads();
    }
    #pragma unroll
    for (int mt = 0; mt < 4; ++mt) {
        #pragma unroll
        for (int nt = 0; nt < 4; ++nt) {
            int col  = n0 + wc + nt * 16 + r;
            int rowb = m0 + wr + mt * 16 + q * 4;
            float bcol = bd[col];
            #pragma unroll
            for (int rr = 0; rr < 4; ++rr) {
                float z = acc[mt][nt][rr] + bcol;
                float sp = (z > 20.f) ? z : log1pf(expf(z));
                sp = fminf(fmaxf(sp, 1e-4f), 0.1f);
                delta[(size_t)(rowb + rr) * DM + col] = sp;
            }
        }
    }
}

// ---------------- fully-fused chunked selective scan ----------------
// Block = 256 threads = 64 chunks x 4 d; grid = BSZ*(DM/4) = 384.
__global__ __launch_bounds__(256) void scan_fused(const float* __restrict__ delta,
                                                  const float* __restrict__ u,
                                                  const float* __restrict__ xp,
                                                  const float* __restrict__ res,
                                                  const float* __restrict__ A_log,
                                                  const float* __restrict__ Dp,
                                                  float* __restrict__ g) {
    __shared__ float sE[NS][NC + 1][4];   // [n][ch][dsub], ch padded to 65
    __shared__ float sH[NS][NC + 1][4];
    __shared__ float sPD[NC][5];
    __shared__ float sTD[4];
    const int tid  = threadIdx.x;
    const int ch   = tid >> 2;
    const int dsub = tid & 3;
    const int blk  = blockIdx.x;
    const int b    = blk / (DM / 4);
    const int d    = (blk % (DM / 4)) * 4 + dsub;
    const int l0   = ch * LC;

    float c[NS];
    #pragma unroll
    for (int n = 0; n < NS; ++n) c[n] = -__expf(A_log[d * NS + n]);

    // ---- phase 1: local scan ----
    float h[NS], ep[NS];
    #pragma unroll
    for (int n = 0; n < NS; ++n) { h[n] = 0.f; ep[n] = 1.f; }
    float pd = 0.f;
    for (int l = 0; l < LC; ++l) {
        size_t rr = (size_t)(b * LSEQ + l0 + l);
        float dlt = delta[rr * DM + d];
        float uu  = u[rr * DM + d];
        pd += dlt;
        float du = dlt * uu;
        f32x4 Bv[4];
        #pragma unroll
        for (int i = 0; i < 4; ++i)
            Bv[i] = *(const f32x4*)(xp + rr * 80 + DR + i * 4);
        #pragma unroll
        for (int n = 0; n < NS; ++n) {
            float e = __expf(c[n] * dlt);
            h[n]  = e * h[n] + du * Bv[n >> 2][n & 3];
            ep[n] *= e;
        }
    }
    #pragma unroll
    for (int n = 0; n < NS; ++n) {
        sE[n][ch][dsub] = ep[n];
        sH[n][ch][dsub] = h[n];
    }
    sPD[ch][dsub] = pd;
    __syncthreads();

    // ---- combine (wave0: H chains; wave1 lanes 0-3: pd prefix) ----
    if (tid < 64) {
        const int ds2 = tid & 3, n2 = tid >> 2;
        float H = 0.f;
        for (int cg = 0; cg < NC; cg += 8) {
            float ee[8], hh[8];
            #pragma unroll
            for (int j = 0; j < 8; ++j) {
                ee[j] = sE[n2][cg + j][ds2];
                hh[j] = sH[n2][cg + j][ds2];
            }
            #pragma unroll
            for (int j = 0; j < 8; ++j) {
                sH[n2][cg + j][ds2] = H;      // H_in for chunk cg+j
                H = ee[j] * H + hh[j];
            }
        }
    } else if (tid < 68) {
        const int ds2 = tid - 64;
        float p = 0.f;
        for (int cg = 0; cg < NC; cg += 8) {
            float ss[8];
            #pragma unroll
            for (int j = 0; j < 8; ++j) ss[j] = sPD[cg + j][ds2];
            #pragma unroll
            for (int j = 0; j < 8; ++j) { sPD[cg + j][ds2] = p; p += ss[j]; }
        }
        sTD[ds2] = p;
    }
    __syncthreads();

    // ---- phase 3: replay + output ----
    #pragma unroll
    for (int n = 0; n < NS; ++n) h[n] = sH[n][ch][dsub];
    pd = sPD[ch][dsub];
    const float td = sTD[dsub];
    const float dp = Dp[d];

    for (int l = 0; l < LC; ++l) {
        size_t rr = (size_t)(b * LSEQ + l0 + l);
        float dlt = delta[rr * DM + d];
        float uu  = u[rr * DM + d];
        float rv  = res[rr * DM + d];
        pd += dlt;
        float du = dlt * uu;
        float x = td - pd;                        // >= 0; exactly 0 at l = L-1
        f32x4 Bv[4], Cv[4];
        #pragma unroll
        for (int i = 0; i < 4; ++i) {
            Bv[i] = *(const f32x4*)(xp + rr * 80 + DR + i * 4);
            Cv[i] = *(const f32x4*)(xp + rr * 80 + DR + NS + i * 4);
        }
        float y = 0.f;
        #pragma unroll
        for (int n = 0; n < NS; ++n) {
            float e = __expf(c[n] * dlt);
            h[n] = e * h[n] + du * Bv[n >> 2][n & 3];
            float P = __expf(-c[n] * x);          // exp(-S); overflow->inf
            float den = 1.0f + 1e-12f * P;        // inf -> corr 0, matches ref
            y += h[n] * Cv[n >> 2][n & 3] * __builtin_amdgcn_rcpf(den);
        }
        y += uu * dp;
        float sig = __builtin_amdgcn_rcpf(1.f + __expf(-rv));
        g[rr * DM + d] = y * rv * sig;
    }
}

extern "C" void kernel_launch(void* const* d_in, const int* in_sizes, int n_in,
                              void* d_out, int out_size, void* d_ws, size_t ws_size,
                              hipStream_t stream) {
    const float* x       = (const float*)d_in[0];
    const float* W_in    = (const float*)d_in[1];
    const float* conv_w  = (const float*)d_in[2];
    const float* conv_b  = (const float*)d_in[3];
    const float* W_x     = (const float*)d_in[4];
    const float* W_delta = (const float*)d_in[5];
    const float* b_delta = (const float*)d_in[6];
    const float* A_log   = (const float*)d_in[7];
    const float* D_param = (const float*)d_in[8];
    const float* W_out   = (const float*)d_in[9];
    float* out = (float*)d_out;
    float* ws  = (float*)d_ws;

    const int R = BSZ * LSEQ;  // 2048

    // Workspace: 28.4 MiB. g aliases u (scan_fused read-before-write).
    float* xs    = ws;                           // R*768
    float* res   = xs    + (size_t)R * DM;       // R*768
    float* u     = res   + (size_t)R * DM;       // R*768
    float* xp    = u     + (size_t)R * DM;       // R*80
    float* delta = xp    + (size_t)R * 80;       // R*768
    float* xpp   = delta + (size_t)R * DM;       // KSP*R*80
    float* g     = u;                            // ALIAS

    // 1) xr = x @ W_in, split epilogue -> xs (cols 0..767), res (cols 768..1535)
    gemm_bf16<<<dim3(1536 / 128, R / 128), 256, 0, stream>>>(
        x, W_in, xs, res, 768, 768, 768, 1536, 768);
    // 2) u = silu(causal depthwise conv(xs) + conv_b)
    conv_silu<<<(R * DM) / 256, 256, 0, stream>>>(xs, conv_w, conv_b, u);
    // 3) xp = u @ W_x — split-K x6 partials, then deterministic reduce
    gemm_wx_sk<<<dim3(R / 64, KSP), 256, 0, stream>>>(u, W_x, xpp);
    reduce_xp<<<(R * 80 / 4) / 256, 256, 0, stream>>>(xpp, xp);
    // 4) delta (bf16 MFMA, K=48 padded, fused softplus epilogue)
    gemm_delta<<<dim3(DM / 128, R / 128), 256, 0, stream>>>(xp, W_delta, b_delta, delta);
    // 5) fully-fused chunked scan + D skip + gate
    scan_fused<<<BSZ * (DM / 4), 256, 0, stream>>>(delta, u, xp, res, A_log, D_param, g);
    // 6) out = g @ W_out
    gemm_bf16<<<dim3(768 / 128, R / 128), 256, 0, stream>>>(
        g, W_out, out, out, 1 << 30, 768, 768, 768, 768);
}